// Round 11
// baseline (43.722 us; speedup 1.0000x reference)
//
#include <hip/hip_runtime.h>
#include <stdint.h>

#define WW 19
#define NP 361
#define M19 0x7FFFFu
#define TPB 256
#define BPC 3                // boards per chunk
#define BPWV 6               // boards per wave (2 chunks)
#define BPB 24               // boards per block (4 waves)
#define PLSTR 97             // u32 stride per board for row planes
#define BMPW 69              // bitmap dwords per wave (2166 bits + pad)

typedef float f32x2 __attribute__((ext_vector_type(2)));

__device__ __forceinline__ uint32_t rev19(uint32_t x) { return __brev(x) >> 13; }

// Fill every horizontal run of m containing a seed of g (g subset of m).
__device__ __forceinline__ uint32_t runfill(uint32_t g, uint32_t m) {
  const uint32_t up = g | (m & ((m + g) ^ m ^ g));
  const uint32_t rm = rev19(m);
  const uint32_t rg = rev19(g);
  const uint32_t dn = rg | (rm & ((rm + rg) ^ rm ^ rg));
  return up | rev19(dn);
}

// 4 independent waves per block; zero __syncthreads. Each wave pipelines two
// 3-board chunks: both chunks' loads issued up front; lib/legal stores issued
// before the flood's serial chain; groups stored after.
__global__ __launch_bounds__(TPB, 4) void go_pipe(
    const float* __restrict__ stones, const int* __restrict__ cur,
    const int* __restrict__ ko, const int* __restrict__ zob,
    const int* __restrict__ zturn, const int* __restrict__ phash,
    float* __restrict__ out, int B) {
  __shared__ uint32_t bmp[4][BMPW];
  __shared__ uint32_t pl[4][BPC * PLSTR];

  const int wid = threadIdx.x >> 6;
  const int lane = threadIdx.x & 63;
  const int gw = blockIdx.x * 4 + wid;   // global wave id
  const size_t NB = (size_t)B * NP;

  // Zobrist tables preloaded (uniform; L1/L2-hot).
  int zb[6], zw[6];
#pragma unroll
  for (int i = 0; i < 6; ++i) {
    const int p = i * 64 + lane;
    zb[i] = (p < NP) ? zob[p] : 0;
    zw[i] = (p < NP) ? zob[NP + p] : 0;
  }
  const int zt = zturn[0] ^ zturn[1];

  const int cb0 = gw * BPWV;       // chunk A base board
  const int cb1 = cb0 + BPC;       // chunk B base board

  // ---- issue ALL loads for both chunks up front (34 independent float2) ----
  f32x2 bufA[17], bufB[17];
  {
    const int nfA = min(BPC, max(0, B - cb0)) * NP;
    const f32x2* srcA = (const f32x2*)(stones + (size_t)cb0 * 722);
#pragma unroll
    for (int j = 0; j < 17; ++j) {
      const int q = j * 64 + lane;
      f32x2 v = {0.0f, 0.0f};
      if (q < nfA) v = srcA[q];
      bufA[j] = v;
    }
    const int nfB = min(BPC, max(0, B - cb1)) * NP;
    const f32x2* srcB = (const f32x2*)(stones + (size_t)cb1 * 722);
#pragma unroll
    for (int j = 0; j < 17; ++j) {
      const int q = j * 64 + lane;
      f32x2 v = {0.0f, 0.0f};
      if (q < nfB) v = srcB[q];
      bufB[j] = v;
    }
  }

  auto process = [&](const f32x2* buf, const int cb) {
    // ---- pack register float2 pairs -> wave-private LDS bitmap -------------
#pragma unroll
    for (int j = 0; j < 17; ++j) {
      const f32x2 v = buf[j];
      const uint32_t m =
          (uint32_t)(v.x > 0.5f) | ((uint32_t)(v.y > 0.5f) << 1);
      uint32_t x = m | ((uint32_t)__shfl_xor((int)m, 1, 64) << 2);
      x |= (uint32_t)__shfl_xor((int)x, 2, 64) << 4;
      x |= (uint32_t)__shfl_xor((int)x, 4, 64) << 8;
      x |= (uint32_t)__shfl_xor((int)x, 8, 64) << 16;
      if ((lane & 15) == 0) bmp[wid][j * 4 + (lane >> 4)] = x;
    }

    // ---- zobrist hash (3 boards per wave) ----------------------------------
    {
      int hv0 = 0, hv1 = 0, hv2 = 0;
#pragma unroll
      for (int i = 0; i < 6; ++i) {
        const int cc = i * 64 + lane;
        if (cc < NP) {
          uint32_t pos, s;
          pos = cc;        s = (bmp[wid][pos >> 5] >> (pos & 31)) & 1u; hv0 ^= zb[i] & -(int)s;
          pos = cc + 361;  s = (bmp[wid][pos >> 5] >> (pos & 31)) & 1u; hv0 ^= zw[i] & -(int)s;
          pos = cc + 722;  s = (bmp[wid][pos >> 5] >> (pos & 31)) & 1u; hv1 ^= zb[i] & -(int)s;
          pos = cc + 1083; s = (bmp[wid][pos >> 5] >> (pos & 31)) & 1u; hv1 ^= zw[i] & -(int)s;
          pos = cc + 1444; s = (bmp[wid][pos >> 5] >> (pos & 31)) & 1u; hv2 ^= zb[i] & -(int)s;
          pos = cc + 1805; s = (bmp[wid][pos >> 5] >> (pos & 31)) & 1u; hv2 ^= zw[i] & -(int)s;
        }
      }
#pragma unroll
      for (int off = 32; off > 0; off >>= 1) {
        hv0 ^= __shfl_xor(hv0, off, 64);
        hv1 ^= __shfl_xor(hv1, off, 64);
        hv2 ^= __shfl_xor(hv2, off, 64);
      }
      if (lane < BPC && cb + lane < B) {
        const int h = (lane == 0) ? hv0 : (lane == 1) ? hv1 : hv2;
        out[3 * NB + cb + lane] = (float)(phash[cb + lane] ^ h ^ zt);
      }
    }

    // ---- row-per-lane algebra ----------------------------------------------
    {
      const int k = (lane * 27) >> 9;  // lane / 19
      const int r = lane - k * WW;
      const int b = cb + k;
      const bool vl = (lane < 57) && (b < B);
      const int ks = vl ? k : 0;

      uint32_t brow, wrow;
      {
        const uint32_t base = (uint32_t)ks * 722 + (uint32_t)r * WW;
        const uint32_t d = base >> 5, sh = base & 31;
        const uint64_t w = ((uint64_t)bmp[wid][d + 1] << 32) | bmp[wid][d];
        brow = (uint32_t)(w >> sh) & M19;
        const uint32_t base2 = base + 361;
        const uint32_t d2 = base2 >> 5, sh2 = base2 & 31;
        const uint64_t w2 = ((uint64_t)bmp[wid][d2 + 1] << 32) | bmp[wid][d2];
        wrow = (uint32_t)(w2 >> sh2) & M19;
      }
      const int cp = vl ? cur[b] : 0;
      int2 kk = {-1, -1};
      if (vl) kk = ((const int2*)ko)[b];
      uint32_t mrow = (cp == 0) ? wrow : brow;
      uint32_t erow = ~(brow | wrow) & M19;
      if (!vl) { mrow = 0; erow = 0; }

      uint32_t t;
      t = __shfl(erow, lane - 1, 64);
      const uint32_t eu = (r > 0) ? t : 0u;
      t = __shfl(erow, lane + 1, 64);
      const uint32_t ed = (r < 18) ? t : 0u;
      const uint32_t el = (erow << 1) & M19;
      const uint32_t er_ = erow >> 1;
      const uint32_t s1 = eu ^ ed, c1 = eu & ed;
      const uint32_t s2 = el ^ er_, c2 = el & er_;
      const uint32_t cc = s1 & s2;
      const uint32_t L0 = s1 ^ s2;
      const uint32_t L1 = c1 ^ c2 ^ cc;
      const uint32_t L2 = (c1 & c2) | (cc & (c1 | c2));
      uint32_t leg = erow & (eu | ed | el | er_);
      const uint32_t vul = mrow & L0 & ~L1;  // liberty count == 1
      t = __shfl(vul, lane - 1, 64);
      const uint32_t vu = (r > 0) ? t : 0u;
      t = __shfl(vul, lane + 1, 64);
      const uint32_t vd = (r < 18) ? t : 0u;
      leg |= erow & (vu | vd | ((vul << 1) & M19) | (vul >> 1));
      if (kk.x == r) leg &= ~(1u << kk.y);

      if (vl) {
        uint32_t* pb = &pl[wid][k * PLSTR];
        pb[r] = L0;
        pb[19 + r] = L1;
        pb[38 + r] = L2;
        pb[57 + r] = leg;
      }

      // ---- EARLY stores: liberties + legal (2/3 of write traffic) ----------
      {
        const int cells = min(BPC, max(0, B - cb)) * NP;
        float* o0 = out + (size_t)cb * NP;
        float* o1 = o0 + NB;
#pragma unroll
        for (int j = 0; j < 17; ++j) {
          const int id = j * 64 + lane;
          if (id < cells) {
            const int k2 = (int)(((uint64_t)id * 5948986ull) >> 31);  // id/361
            const int p = id - k2 * NP;
            const int r2 = (p * 27) >> 9;
            const int c2 = p - r2 * WW;
            const uint32_t* pb = &pl[wid][k2 * PLSTR];
            const uint32_t l0 = (pb[r2] >> c2) & 1u;
            const uint32_t l1 = (pb[19 + r2] >> c2) & 1u;
            const uint32_t l2 = (pb[38 + r2] >> c2) & 1u;
            __builtin_nontemporal_store((float)(l0 + 2u * l1 + 4u * l2),
                                        &o0[id]);
            __builtin_nontemporal_store((float)((pb[57 + r2] >> c2) & 1u),
                                        &o1[id]);
          }
        }
      }

      // ---- flood fill (serial chain overlaps store drain above) ------------
      uint32_t g = runfill(vul, mrow);
      for (int it = 0; it < 90; ++it) {
        t = __shfl(g, lane - 1, 64);
        const uint32_t gu = (r > 0) ? t : 0u;
        t = __shfl(g, lane + 1, 64);
        const uint32_t gd = (r < 18) ? t : 0u;
        const uint32_t gn = runfill(g | ((gu | gd) & mrow), mrow);
        if (!__any(gn != g)) break;
        g = gn;
      }
      if (vl) pl[wid][k * PLSTR + 76 + r] = g;
    }

    // ---- LATE stores: groups plane -----------------------------------------
    {
      const int cells = min(BPC, max(0, B - cb)) * NP;
      float* o2 = out + 2 * NB + (size_t)cb * NP;
#pragma unroll
      for (int j = 0; j < 17; ++j) {
        const int id = j * 64 + lane;
        if (id < cells) {
          const int k2 = (int)(((uint64_t)id * 5948986ull) >> 31);
          const int p = id - k2 * NP;
          const int r2 = (p * 27) >> 9;
          const int c2 = p - r2 * WW;
          __builtin_nontemporal_store(
              (float)((pl[wid][k2 * PLSTR + 76 + r2] >> c2) & 1u), &o2[id]);
        }
      }
    }
  };

  process(bufA, cb0);
  process(bufB, cb1);
}

extern "C" void kernel_launch(void* const* d_in, const int* in_sizes, int n_in,
                              void* d_out, int out_size, void* d_ws,
                              size_t ws_size, hipStream_t stream) {
  const float* stones = (const float*)d_in[0];
  const int* cur = (const int*)d_in[1];
  const int* ko = (const int*)d_in[2];
  const int* zob = (const int*)d_in[3];
  const int* zturn = (const int*)d_in[4];
  const int* phash = (const int*)d_in[5];
  float* out = (float*)d_out;

  const int B = in_sizes[0] / (2 * NP);
  const int blocks = (B + BPB - 1) / BPB;
  go_pipe<<<blocks, TPB, 0, stream>>>(stones, cur, ko, zob, zturn, phash, out,
                                      B);
}

// Round 12
// 34.043 us; speedup vs baseline: 1.2843x; 1.2843x over previous
//
#include <hip/hip_runtime.h>
#include <stdint.h>

#define WW 19
#define NP 361
#define M19 0x7FFFFu
#define BPW 3                  // boards per wave in row phase
#define BPB 12                 // boards per block (k1)
#define TPB 256
#define CH4 (BPB * 722 / 4)    // 2166 float4s per full chunk
#define BMW 272                // bitmap dwords (8664 bits -> 271, +1 pad)
#define RSTR 96                // u32 record stride per board in ws (384 B)
#define BPB2 16                // boards per block (k2)
#define PLSTR 97               // (fallback kernel)

typedef float f32x4 __attribute__((ext_vector_type(4)));

__device__ __forceinline__ uint32_t rev19(uint32_t x) { return __brev(x) >> 13; }

__device__ __forceinline__ uint32_t runfill(uint32_t g, uint32_t m) {
  const uint32_t up = g | (m & ((m + g) ^ m ^ g));
  const uint32_t rm = rev19(m);
  const uint32_t rg = rev19(g);
  const uint32_t dn = rg | (rm & ((rm + rg) ^ rm ^ rg));
  return up | rev19(dn);
}

// ================= K1: pack + hash + algebra + flood -> ws records ===========
__global__ __launch_bounds__(TPB, 4) void k1_compute(
    const float* __restrict__ stones, const int* __restrict__ cur,
    const int* __restrict__ ko, const int* __restrict__ zob,
    const int* __restrict__ zturn, const int* __restrict__ phash,
    float* __restrict__ out, uint32_t* __restrict__ ws, int B) {
  __shared__ uint32_t bmp[BMW];  // linear stone bitmap: cell i = bit i

  const int wid = threadIdx.x >> 6;
  const int lane = threadIdx.x & 63;
  const int b0 = blockIdx.x * BPB;
  const int nb = min(BPB, B - b0);
  const size_t NB = (size_t)B * NP;

  int zb[6], zw[6];
#pragma unroll
  for (int i = 0; i < 6; ++i) {
    const int p = i * 64 + lane;
    zb[i] = (p < NP) ? zob[p] : 0;
    zw[i] = (p < NP) ? zob[NP + p] : 0;
  }
  const int zt = zturn[0] ^ zturn[1];

  // pack: float4 loads -> nibbles -> LDS bitmap
  {
    const f32x4* src = (const f32x4*)(stones + (size_t)b0 * 722);
    const int nf4 = nb * 722 / 4;
    for (int j = 0; j < (CH4 + TPB - 1) / TPB; ++j) {
      const int q = threadIdx.x + TPB * j;
      uint32_t m = 0;
      if (q < nf4) {
        const f32x4 v = src[q];
        m = (uint32_t)(v.x > 0.5f) | ((uint32_t)(v.y > 0.5f) << 1) |
            ((uint32_t)(v.z > 0.5f) << 2) | ((uint32_t)(v.w > 0.5f) << 3);
      }
      uint32_t x = m | ((uint32_t)__shfl_xor((int)m, 1, 64) << 4);
      x = x | ((uint32_t)__shfl_xor((int)x, 2, 64) << 8);
      x = x | ((uint32_t)__shfl_xor((int)x, 4, 64) << 16);
      if ((lane & 7) == 0 && q < CH4) bmp[q >> 3] = x;
    }
  }
  __syncthreads();

  // zobrist hash from bitmap (wave per 3 boards)
  {
    int hv[BPW];
#pragma unroll
    for (int k = 0; k < BPW; ++k) {
      const int lb = wid * BPW + k;
      const uint32_t base = lb * 722;
      int h = 0;
#pragma unroll
      for (int i = 0; i < 6; ++i) {
        const int cc = i * 64 + lane;
        if (cc < NP) {
          uint32_t pos = base + cc;
          uint32_t s = (bmp[pos >> 5] >> (pos & 31)) & 1u;
          h ^= zb[i] & -(int)s;
          pos = base + 361 + cc;
          s = (bmp[pos >> 5] >> (pos & 31)) & 1u;
          h ^= zw[i] & -(int)s;
        }
      }
      hv[k] = h;
    }
#pragma unroll
    for (int off = 32; off > 0; off >>= 1) {
#pragma unroll
      for (int k = 0; k < BPW; ++k) hv[k] ^= __shfl_xor(hv[k], off, 64);
    }
    if (lane == 0) {
#pragma unroll
      for (int k = 0; k < BPW; ++k) {
        const int b = b0 + wid * BPW + k;
        if (b < B) out[3 * NB + b] = (float)(phash[b] ^ hv[k] ^ zt);
      }
    }
  }

  // row-per-lane algebra + flood -> ws record stores
  {
    const int k = (lane * 27) >> 9;  // lane / 19
    const int r = lane - k * WW;
    const int lb = wid * BPW + k;
    const int b = b0 + lb;
    const bool vl = (lane < 57) && (lb < nb);
    const int lbs = vl ? lb : 0;

    uint32_t brow, wrow;
    {
      const uint32_t base = (uint32_t)lbs * 722 + (uint32_t)r * WW;
      const uint32_t d = base >> 5, sh = base & 31;
      const uint64_t w = ((uint64_t)bmp[d + 1] << 32) | bmp[d];
      brow = (uint32_t)(w >> sh) & M19;
      const uint32_t base2 = base + 361;
      const uint32_t d2 = base2 >> 5, sh2 = base2 & 31;
      const uint64_t w2 = ((uint64_t)bmp[d2 + 1] << 32) | bmp[d2];
      wrow = (uint32_t)(w2 >> sh2) & M19;
    }
    const int cp = vl ? cur[b] : 0;
    int2 kk = {-1, -1};
    if (vl) kk = ((const int2*)ko)[b];
    uint32_t mrow = (cp == 0) ? wrow : brow;
    uint32_t erow = ~(brow | wrow) & M19;
    if (!vl) { mrow = 0; erow = 0; }

    uint32_t t;
    t = __shfl(erow, lane - 1, 64);
    const uint32_t eu = (r > 0) ? t : 0u;
    t = __shfl(erow, lane + 1, 64);
    const uint32_t ed = (r < 18) ? t : 0u;
    const uint32_t el = (erow << 1) & M19;
    const uint32_t er_ = erow >> 1;
    const uint32_t s1 = eu ^ ed, c1 = eu & ed;
    const uint32_t s2 = el ^ er_, c2 = el & er_;
    const uint32_t cc = s1 & s2;
    const uint32_t L0 = s1 ^ s2;
    const uint32_t L1 = c1 ^ c2 ^ cc;
    const uint32_t L2 = (c1 & c2) | (cc & (c1 | c2));
    uint32_t leg = erow & (eu | ed | el | er_);
    const uint32_t vul = mrow & L0 & ~L1;
    t = __shfl(vul, lane - 1, 64);
    const uint32_t vu = (r > 0) ? t : 0u;
    t = __shfl(vul, lane + 1, 64);
    const uint32_t vd = (r < 18) ? t : 0u;
    leg |= erow & (vu | vd | ((vul << 1) & M19) | (vul >> 1));
    if (kk.x == r) leg &= ~(1u << kk.y);

    uint32_t g = runfill(vul, mrow);
    for (int it = 0; it < 90; ++it) {
      t = __shfl(g, lane - 1, 64);
      const uint32_t gu = (r > 0) ? t : 0u;
      t = __shfl(g, lane + 1, 64);
      const uint32_t gd = (r < 18) ? t : 0u;
      const uint32_t gn = runfill(g | ((gu | gd) & mrow), mrow);
      if (!__any(gn != g)) break;
      g = gn;
    }

    if (vl) {
      uint32_t* w = ws + (size_t)b * RSTR;
      w[r] = L0;
      w[19 + r] = L1;
      w[38 + r] = L2;
      w[57 + r] = leg;
      w[76 + r] = g;
    }
  }
}

// ================= K2: pure streaming expander (ws -> float outputs) =========
__global__ __launch_bounds__(TPB, 4) void k2_expand(
    const uint32_t* __restrict__ ws, float* __restrict__ out, int B) {
  __shared__ uint32_t rec[BPB2 * RSTR];  // 1536 dwords = 6 KB

  const int b0 = blockIdx.x * BPB2;
  const int nb = min(BPB2, B - b0);
  const size_t NB = (size_t)B * NP;

  // coalesced uint4 record load (block chunk is 6144 B, 16B-aligned)
  {
    const uint4* src = (const uint4*)(ws + (size_t)b0 * RSTR);
    uint4* dst = (uint4*)rec;
#pragma unroll
    for (int jj = 0; jj < 2; ++jj) {
      const int q = threadIdx.x + TPB * jj;
      if (q < BPB2 * RSTR / 4) dst[q] = src[q];
    }
  }
  __syncthreads();

  const int nq = nb * NP / 4;  // nb multiple of 4 for all real blocks
  f32x4* s0 = (f32x4*)(out + (size_t)b0 * NP);
  f32x4* s1 = (f32x4*)(out + NB + (size_t)b0 * NP);
  f32x4* s2 = (f32x4*)(out + 2 * NB + (size_t)b0 * NP);
  for (int q = threadIdx.x; q < nq; q += TPB) {
    f32x4 t0, t1, t2;
#pragma unroll
    for (int j = 0; j < 4; ++j) {
      const int id = q * 4 + j;
      const int lb = (int)(((uint64_t)id * 5948986ull) >> 31);  // id/361
      const int p = id - lb * NP;
      const int r = (p * 27) >> 9;  // p/19 for p<512
      const int c = p - r * WW;
      const uint32_t* pb = &rec[lb * RSTR];
      const uint32_t l0 = (pb[r] >> c) & 1u;
      const uint32_t l1 = (pb[19 + r] >> c) & 1u;
      const uint32_t l2 = (pb[38 + r] >> c) & 1u;
      t0[j] = (float)(l0 + 2u * l1 + 4u * l2);
      t1[j] = (float)((pb[57 + r] >> c) & 1u);
      t2[j] = (float)((pb[76 + r] >> c) & 1u);
    }
    __builtin_nontemporal_store(t0, &s0[q]);
    __builtin_nontemporal_store(t1, &s1[q]);
    __builtin_nontemporal_store(t2, &s2[q]);
  }
  // safety tail (never taken for B multiple of 4)
  const int rem0 = nq * 4;
  for (int id = rem0 + threadIdx.x; id < nb * NP; id += TPB) {
    const int lb = (int)(((uint64_t)id * 5948986ull) >> 31);
    const int p = id - lb * NP;
    const int r = (p * 27) >> 9;
    const int c = p - r * WW;
    const uint32_t* pb = &rec[lb * RSTR];
    const uint32_t l0 = (pb[r] >> c) & 1u;
    const uint32_t l1 = (pb[19 + r] >> c) & 1u;
    const uint32_t l2 = (pb[38 + r] >> c) & 1u;
    out[(size_t)b0 * NP + id] = (float)(l0 + 2u * l1 + 4u * l2);
    out[NB + (size_t)b0 * NP + id] = (float)((pb[57 + r] >> c) & 1u);
    out[2 * NB + (size_t)b0 * NP + id] = (float)((pb[76 + r] >> c) & 1u);
  }
}

// ================= fallback: R10 fused kernel (if ws too small) ==============
__global__ __launch_bounds__(TPB, 4) void go_fused(
    const float* __restrict__ stones, const int* __restrict__ cur,
    const int* __restrict__ ko, const int* __restrict__ zob,
    const int* __restrict__ zturn, const int* __restrict__ phash,
    float* __restrict__ out, int B) {
  __shared__ float stg[BPB * 722];
  __shared__ uint32_t pl[BPB * PLSTR];

  const int wid = threadIdx.x >> 6;
  const int lane = threadIdx.x & 63;
  const int b0 = blockIdx.x * BPB;
  const int nb = min(BPB, B - b0);
  const size_t NB = (size_t)B * NP;

  int zb[6], zw[6];
#pragma unroll
  for (int i = 0; i < 6; ++i) {
    const int p = i * 64 + lane;
    zb[i] = (p < NP) ? zob[p] : 0;
    zw[i] = (p < NP) ? zob[NP + p] : 0;
  }
  const int zt = zturn[0] ^ zturn[1];

  {
    const uint32_t nfl = (uint32_t)nb * 722u;
    const float* gsrc = stones + (size_t)b0 * 722;
#pragma unroll
    for (int rnd = 0; rnd < 9; ++rnd) {
      const uint32_t fo = (uint32_t)rnd * 1024u + (uint32_t)wid * 256u +
                          (uint32_t)lane * 4u;
      if (fo < nfl) {
        __builtin_amdgcn_global_load_lds(
            (const __attribute__((address_space(1))) uint32_t*)(gsrc + fo),
            (__attribute__((address_space(3))) uint32_t*)(stg + rnd * 1024 +
                                                          wid * 256),
            16, 0, 0);
      }
    }
  }
  __syncthreads();

  {
    int hv[BPW];
#pragma unroll
    for (int k = 0; k < BPW; ++k) {
      const int lb = wid * BPW + k;
      const int base = lb * 722;
      int h = 0;
#pragma unroll
      for (int i = 0; i < 6; ++i) {
        const int cc = i * 64 + lane;
        if (cc < NP) {
          const uint32_t sb = stg[base + cc] > 0.5f;
          const uint32_t sw = stg[base + 361 + cc] > 0.5f;
          h ^= zb[i] & -(int)sb;
          h ^= zw[i] & -(int)sw;
        }
      }
      hv[k] = h;
    }
#pragma unroll
    for (int off = 32; off > 0; off >>= 1) {
#pragma unroll
      for (int k = 0; k < BPW; ++k) hv[k] ^= __shfl_xor(hv[k], off, 64);
    }
    if (lane == 0) {
#pragma unroll
      for (int k = 0; k < BPW; ++k) {
        const int b = b0 + wid * BPW + k;
        if (b < B) out[3 * NB + b] = (float)(phash[b] ^ hv[k] ^ zt);
      }
    }
  }

  {
    const int k = (lane * 27) >> 9;
    const int r = lane - k * WW;
    const int lb = wid * BPW + k;
    const int b = b0 + lb;
    const bool vl = (lane < 57) && (lb < nb);
    const int lbs = vl ? lb : 0;

    uint32_t brow = 0, wrow = 0;
    {
      const float* rb = &stg[lbs * 722 + r * WW];
#pragma unroll
      for (int c = 0; c < WW; ++c) {
        brow |= (uint32_t)(rb[c] > 0.5f) << c;
        wrow |= (uint32_t)(rb[361 + c] > 0.5f) << c;
      }
    }
    const int cp = vl ? cur[b] : 0;
    int2 kk = {-1, -1};
    if (vl) kk = ((const int2*)ko)[b];
    uint32_t mrow = (cp == 0) ? wrow : brow;
    uint32_t erow = ~(brow | wrow) & M19;
    if (!vl) { mrow = 0; erow = 0; }

    uint32_t t;
    t = __shfl(erow, lane - 1, 64);
    const uint32_t eu = (r > 0) ? t : 0u;
    t = __shfl(erow, lane + 1, 64);
    const uint32_t ed = (r < 18) ? t : 0u;
    const uint32_t el = (erow << 1) & M19;
    const uint32_t er_ = erow >> 1;
    const uint32_t s1 = eu ^ ed, c1 = eu & ed;
    const uint32_t s2 = el ^ er_, c2 = el & er_;
    const uint32_t cc = s1 & s2;
    const uint32_t L0 = s1 ^ s2;
    const uint32_t L1 = c1 ^ c2 ^ cc;
    const uint32_t L2 = (c1 & c2) | (cc & (c1 | c2));
    uint32_t leg = erow & (eu | ed | el | er_);
    const uint32_t vul = mrow & L0 & ~L1;
    t = __shfl(vul, lane - 1, 64);
    const uint32_t vu = (r > 0) ? t : 0u;
    t = __shfl(vul, lane + 1, 64);
    const uint32_t vd = (r < 18) ? t : 0u;
    leg |= erow & (vu | vd | ((vul << 1) & M19) | (vul >> 1));
    if (kk.x == r) leg &= ~(1u << kk.y);

    uint32_t g = runfill(vul, mrow);
    for (int it = 0; it < 90; ++it) {
      t = __shfl(g, lane - 1, 64);
      const uint32_t gu = (r > 0) ? t : 0u;
      t = __shfl(g, lane + 1, 64);
      const uint32_t gd = (r < 18) ? t : 0u;
      const uint32_t gn = runfill(g | ((gu | gd) & mrow), mrow);
      if (!__any(gn != g)) break;
      g = gn;
    }

    if (vl) {
      uint32_t* pb = &pl[lb * PLSTR];
      pb[r] = L0;
      pb[19 + r] = L1;
      pb[38 + r] = L2;
      pb[57 + r] = leg;
      pb[76 + r] = g;
    }
  }
  __syncthreads();

  {
    const int nq = nb * NP / 4;
    f32x4* s0 = (f32x4*)(out + (size_t)b0 * NP);
    f32x4* s1 = (f32x4*)(out + NB + (size_t)b0 * NP);
    f32x4* s2 = (f32x4*)(out + 2 * NB + (size_t)b0 * NP);
    for (int q = threadIdx.x; q < nq; q += TPB) {
      f32x4 t0, t1, t2;
#pragma unroll
      for (int j = 0; j < 4; ++j) {
        const int id = q * 4 + j;
        const int lb = (int)(((uint64_t)id * 5948986ull) >> 31);
        const int p = id - lb * NP;
        const int r = (p * 27) >> 9;
        const int c = p - r * WW;
        const uint32_t* pb = &pl[lb * PLSTR];
        const uint32_t l0 = (pb[r] >> c) & 1u;
        const uint32_t l1 = (pb[19 + r] >> c) & 1u;
        const uint32_t l2 = (pb[38 + r] >> c) & 1u;
        t0[j] = (float)(l0 + 2u * l1 + 4u * l2);
        t1[j] = (float)((pb[57 + r] >> c) & 1u);
        t2[j] = (float)((pb[76 + r] >> c) & 1u);
      }
      __builtin_nontemporal_store(t0, &s0[q]);
      __builtin_nontemporal_store(t1, &s1[q]);
      __builtin_nontemporal_store(t2, &s2[q]);
    }
    const int rem0 = nq * 4;
    for (int id = rem0 + threadIdx.x; id < nb * NP; id += TPB) {
      const int lb = (int)(((uint64_t)id * 5948986ull) >> 31);
      const int p = id - lb * NP;
      const int r = (p * 27) >> 9;
      const int c = p - r * WW;
      const uint32_t* pb = &pl[lb * PLSTR];
      const uint32_t l0 = (pb[r] >> c) & 1u;
      const uint32_t l1 = (pb[19 + r] >> c) & 1u;
      const uint32_t l2 = (pb[38 + r] >> c) & 1u;
      out[(size_t)b0 * NP + id] = (float)(l0 + 2u * l1 + 4u * l2);
      out[NB + (size_t)b0 * NP + id] = (float)((pb[57 + r] >> c) & 1u);
      out[2 * NB + (size_t)b0 * NP + id] = (float)((pb[76 + r] >> c) & 1u);
    }
  }
}

extern "C" void kernel_launch(void* const* d_in, const int* in_sizes, int n_in,
                              void* d_out, int out_size, void* d_ws,
                              size_t ws_size, hipStream_t stream) {
  const float* stones = (const float*)d_in[0];
  const int* cur = (const int*)d_in[1];
  const int* ko = (const int*)d_in[2];
  const int* zob = (const int*)d_in[3];
  const int* zturn = (const int*)d_in[4];
  const int* phash = (const int*)d_in[5];
  float* out = (float*)d_out;

  const int B = in_sizes[0] / (2 * NP);
  const size_t need = (size_t)B * (RSTR * 4);

  if (ws_size >= need) {
    uint32_t* ws = (uint32_t*)d_ws;
    k1_compute<<<(B + BPB - 1) / BPB, TPB, 0, stream>>>(stones, cur, ko, zob,
                                                        zturn, phash, out, ws,
                                                        B);
    k2_expand<<<(B + BPB2 - 1) / BPB2, TPB, 0, stream>>>(ws, out, B);
  } else {
    go_fused<<<(B + BPB - 1) / BPB, TPB, 0, stream>>>(stones, cur, ko, zob,
                                                      zturn, phash, out, B);
  }
}

// Round 13
// 28.506 us; speedup vs baseline: 1.5338x; 1.1943x over previous
//
#include <hip/hip_runtime.h>
#include <stdint.h>

#define WW 19
#define NP 361
#define M19 0x7FFFFu
#define BPW 3                 // boards per wave in row phase (3*19 = 57 lanes)
#define BPB 12                // boards per block
#define TPB 256
#define STGF (BPB * 722)      // 8664 staged floats
#define P64 40                // u64 stride per board: 19 lib + 19 lg + 2 pad

typedef float f32x4 __attribute__((ext_vector_type(4)));

__device__ __forceinline__ uint32_t rev19(uint32_t x) { return __brev(x) >> 13; }

// Fill every horizontal run of m containing a seed of g (g subset of m).
__device__ __forceinline__ uint32_t runfill(uint32_t g, uint32_t m) {
  const uint32_t up = g | (m & ((m + g) ^ m ^ g));
  const uint32_t rm = rev19(m);
  const uint32_t rg = rev19(g);
  const uint32_t dn = rg | (rm & ((rm + rg) ^ rm ^ rg));
  return up | rev19(dn);
}

// Bit-spread: 19-bit mask -> every 3rd bit of a 57-bit value (Morton-3).
__device__ __forceinline__ uint64_t spr3(uint32_t v) {
  uint64_t x = v;
  x = (x | (x << 32)) & 0x1f00000000ffffull;
  x = (x | (x << 16)) & 0x1f0000ff0000ffull;
  x = (x | (x << 8)) & 0x100f00f00f00f00full;
  x = (x | (x << 4)) & 0x10c30c30c30c30c3ull;
  x = (x | (x << 2)) & 0x1249249249249249ull;
  return x;
}
// Bit-spread: 19-bit mask -> every 2nd bit (Morton-2).
__device__ __forceinline__ uint64_t spr2(uint32_t v) {
  uint64_t x = v;
  x = (x | (x << 16)) & 0x0000ffff0000ffffull;
  x = (x | (x << 8)) & 0x00ff00ff00ff00ffull;
  x = (x | (x << 4)) & 0x0f0f0f0f0f0f0f0full;
  x = (x | (x << 2)) & 0x3333333333333333ull;
  x = (x | (x << 1)) & 0x5555555555555555ull;
  return x;
}

__global__ __launch_bounds__(TPB, 4) void go_fused(
    const float* __restrict__ stones, const int* __restrict__ cur,
    const int* __restrict__ ko, const int* __restrict__ zob,
    const int* __restrict__ zturn, const int* __restrict__ phash,
    float* __restrict__ out, int B) {
  __shared__ float stg[STGF];            // raw staged stone floats (12 boards)
  __shared__ uint64_t pl64[BPB * P64];   // packed planes: [0..18] lib3, [19..37] leg|grp

  const int wid = threadIdx.x >> 6;
  const int lane = threadIdx.x & 63;
  const int b0 = blockIdx.x * BPB;
  const int nb = min(BPB, B - b0);
  const size_t NB = (size_t)B * NP;

  // Zobrist tables preloaded into registers (uniform across blocks, cached).
  int zb[6], zw[6];
#pragma unroll
  for (int i = 0; i < 6; ++i) {
    const int p = i * 64 + lane;
    zb[i] = (p < NP) ? zob[p] : 0;
    zw[i] = (p < NP) ? zob[NP + p] : 0;
  }
  const int zt = zturn[0] ^ zturn[1];

  // ---------------- phase 1: async global->LDS staging (raw floats) ---------
  {
    const uint32_t nfl = (uint32_t)nb * 722u;
    const float* gsrc = stones + (size_t)b0 * 722;
#pragma unroll
    for (int rnd = 0; rnd < 9; ++rnd) {
      const uint32_t fo = (uint32_t)rnd * 1024u + (uint32_t)wid * 256u +
                          (uint32_t)lane * 4u;
      if (fo < nfl) {
        __builtin_amdgcn_global_load_lds(
            (const __attribute__((address_space(1))) uint32_t*)(gsrc + fo),
            (__attribute__((address_space(3))) uint32_t*)(stg + rnd * 1024 +
                                                          wid * 256),
            16, 0, 0);
      }
    }
  }
  __syncthreads();  // drains vmcnt; staged floats visible block-wide

  // ---------------- phase 1.5: zobrist hash from staged floats --------------
  {
    int hv[BPW];
#pragma unroll
    for (int k = 0; k < BPW; ++k) {
      const int lb = wid * BPW + k;
      const int base = lb * 722;
      int h = 0;
#pragma unroll
      for (int i = 0; i < 6; ++i) {
        const int cc = i * 64 + lane;
        if (cc < NP) {
          const uint32_t sb = stg[base + cc] > 0.5f;
          const uint32_t sw = stg[base + 361 + cc] > 0.5f;
          h ^= zb[i] & -(int)sb;
          h ^= zw[i] & -(int)sw;
        }
      }
      hv[k] = h;
    }
#pragma unroll
    for (int off = 32; off > 0; off >>= 1) {
#pragma unroll
      for (int k = 0; k < BPW; ++k) hv[k] ^= __shfl_xor(hv[k], off, 64);
    }
    if (lane == 0) {
#pragma unroll
      for (int k = 0; k < BPW; ++k) {
        const int b = b0 + wid * BPW + k;
        if (b < B) out[3 * NB + b] = (float)(phash[b] ^ hv[k] ^ zt);
      }
    }
  }

  // ---------------- phase 2: row-per-lane algebra + flood -> packed planes --
  {
    const int k = (lane * 27) >> 9;  // lane / 19
    const int r = lane - k * WW;
    const int lb = wid * BPW + k;
    const int b = b0 + lb;
    const bool vl = (lane < 57) && (lb < nb);
    const int lbs = vl ? lb : 0;

    // Build this lane's black/white rows from staged floats.
    uint32_t brow = 0, wrow = 0;
    {
      const float* rb = &stg[lbs * 722 + r * WW];
#pragma unroll
      for (int c = 0; c < WW; ++c) {
        brow |= (uint32_t)(rb[c] > 0.5f) << c;
        wrow |= (uint32_t)(rb[361 + c] > 0.5f) << c;
      }
    }
    const int cp = vl ? cur[b] : 0;
    int2 kk = {-1, -1};
    if (vl) kk = ((const int2*)ko)[b];
    uint32_t mrow = (cp == 0) ? wrow : brow;
    uint32_t erow = ~(brow | wrow) & M19;
    if (!vl) { mrow = 0; erow = 0; }

    // Liberties / legal / vulnerable (vertical neighbors via shfl).
    uint32_t t;
    t = __shfl(erow, lane - 1, 64);
    const uint32_t eu = (r > 0) ? t : 0u;
    t = __shfl(erow, lane + 1, 64);
    const uint32_t ed = (r < 18) ? t : 0u;
    const uint32_t el = (erow << 1) & M19;
    const uint32_t er_ = erow >> 1;
    const uint32_t s1 = eu ^ ed, c1 = eu & ed;
    const uint32_t s2 = el ^ er_, c2 = el & er_;
    const uint32_t cc = s1 & s2;
    const uint32_t L0 = s1 ^ s2;
    const uint32_t L1 = c1 ^ c2 ^ cc;
    const uint32_t L2 = (c1 & c2) | (cc & (c1 | c2));
    uint32_t leg = erow & (eu | ed | el | er_);
    const uint32_t vul = mrow & L0 & ~L1;  // liberty count == 1
    t = __shfl(vul, lane - 1, 64);
    const uint32_t vu = (r > 0) ? t : 0u;
    t = __shfl(vul, lane + 1, 64);
    const uint32_t vd = (r < 18) ? t : 0u;
    leg |= erow & (vu | vd | ((vul << 1) & M19) | (vul >> 1));
    if (kk.x == r) leg &= ~(1u << kk.y);

    // Pack + store liberty plane now (releases L0/L1/L2 before flood).
    if (vl)
      pl64[lb * P64 + r] = spr3(L0) | (spr3(L1) << 1) | (spr3(L2) << 2);

    // Flood fill: horizontal runfill + vertical shfl step, early exit.
    uint32_t g = runfill(vul, mrow);
    for (int it = 0; it < 90; ++it) {
      t = __shfl(g, lane - 1, 64);
      const uint32_t gu = (r > 0) ? t : 0u;
      t = __shfl(g, lane + 1, 64);
      const uint32_t gd = (r < 18) ? t : 0u;
      const uint32_t gn = runfill(g | ((gu | gd) & mrow), mrow);
      if (!__any(gn != g)) break;
      g = gn;
    }

    if (vl) pl64[lb * P64 + 19 + r] = spr2(leg) | (spr2(g) << 1);
  }
  __syncthreads();

  // ---------------- phase 3: expand packed planes -> plain float4 stores ----
  {
    const int nq = nb * NP / 4;  // nb in {12,4} -> always divisible
    f32x4* s0 = (f32x4*)(out + (size_t)b0 * NP);
    f32x4* s1 = (f32x4*)(out + NB + (size_t)b0 * NP);
    f32x4* s2 = (f32x4*)(out + 2 * NB + (size_t)b0 * NP);
    for (int q = threadIdx.x; q < nq; q += TPB) {
      f32x4 t0, t1, t2;
#pragma unroll
      for (int j = 0; j < 4; ++j) {
        const int id = q * 4 + j;
        const int lb = (int)(((uint64_t)id * 5948986ull) >> 31);  // id/361
        const int p = id - lb * NP;
        const int r = (p * 27) >> 9;  // p/19 for p<512
        const int c = p - r * WW;
        const uint64_t lib = pl64[lb * P64 + r];
        const uint64_t lg = pl64[lb * P64 + 19 + r];
        t0[j] = (float)((uint32_t)(lib >> (3 * c)) & 7u);
        const uint32_t lgv = (uint32_t)(lg >> (2 * c));
        t1[j] = (float)(lgv & 1u);
        t2[j] = (float)((lgv >> 1) & 1u);
      }
      s0[q] = t0;
      s1[q] = t1;
      s2[q] = t2;
    }
    // Generic remainder guard (never taken for nb in {12,4}; safety only).
    const int rem0 = nq * 4;
    for (int id = rem0 + threadIdx.x; id < nb * NP; id += TPB) {
      const int lb = (int)(((uint64_t)id * 5948986ull) >> 31);
      const int p = id - lb * NP;
      const int r = (p * 27) >> 9;
      const int c = p - r * WW;
      const uint64_t lib = pl64[lb * P64 + r];
      const uint64_t lg = pl64[lb * P64 + 19 + r];
      out[(size_t)b0 * NP + id] = (float)((uint32_t)(lib >> (3 * c)) & 7u);
      const uint32_t lgv = (uint32_t)(lg >> (2 * c));
      out[NB + (size_t)b0 * NP + id] = (float)(lgv & 1u);
      out[2 * NB + (size_t)b0 * NP + id] = (float)((lgv >> 1) & 1u);
    }
  }
}

extern "C" void kernel_launch(void* const* d_in, const int* in_sizes, int n_in,
                              void* d_out, int out_size, void* d_ws,
                              size_t ws_size, hipStream_t stream) {
  const float* stones = (const float*)d_in[0];
  const int* cur = (const int*)d_in[1];
  const int* ko = (const int*)d_in[2];
  const int* zob = (const int*)d_in[3];
  const int* zturn = (const int*)d_in[4];
  const int* phash = (const int*)d_in[5];
  float* out = (float*)d_out;

  const int B = in_sizes[0] / (2 * NP);
  const int blocks = (B + BPB - 1) / BPB;
  go_fused<<<blocks, TPB, 0, stream>>>(stones, cur, ko, zob, zturn, phash, out,
                                       B);
}